// Round 5
// baseline (165.236 us; speedup 1.0000x reference)
//
#include <hip/hip_runtime.h>
#include <math.h>

#define B_GRAPHS 4096
#define NPG 64
#define E_DIM 128
#define INV_B (1.0f / 4096.0f)

static __device__ __forceinline__ float4 fmax4(float4 a, float4 b) {
    return make_float4(fmaxf(a.x, b.x), fmaxf(a.y, b.y),
                       fmaxf(a.z, b.z), fmaxf(a.w, b.w));
}

// ---------------------------------------------------------------------------
// One block per graph (4096 blocks x 256 threads).
//  Phase 1: gather 64+64 rows, 16 float4 loads/thread issued into named regs
//           (launch_bounds(256,6) -> ~84 VGPR cap so ~12 stay in flight),
//           register tree-max, shfl_xor(32) pre-reduce, SoA scalar LDS store
//           (conflict-free: lane -> bank identity).
//  Phase 2: 64 threads reduce 4 wave-partials -> pooled P4[2][32].
//  Phase 3: matvec (side=t&1, e=t>>1), W rows streamed from L1/L2.
//  Phase 4: pair shfl_xor(1) -> per-lane (l,r); full-wave xor reduce of
//           dot/nl/nr; 4-entry LDS combine; thread 0 -> cos + atomic loss.
// ---------------------------------------------------------------------------
__global__ __launch_bounds__(256, 6) void fused_graph_sim_k(
    const int* __restrict__ lx, const int* __restrict__ rx,
    const float* __restrict__ emb, const float* __restrict__ W,
    const float* __restrict__ bias, const float* __restrict__ label,
    float* __restrict__ out)
{
    const int g    = blockIdx.x;
    const int t    = threadIdx.x;
    const int w    = t >> 6;
    const int lane = t & 63;

    __shared__ int   idxL[NPG], idxR[NPG];
    __shared__ float red[2][4][E_DIM];   // [side][component][w*32+q], SoA
    __shared__ float4 P4[2][32];         // pooled, float4 view of [2][128]
    __shared__ float wred[3][4];         // per-wave dot/nl/nr partials

    if (t < NPG)          idxL[t]       = lx[g * NPG + t];
    else if (t < 2 * NPG) idxR[t - NPG] = rx[g * NPG + (t - NPG)];
    __syncthreads();

    const int n0 = t >> 5;   // node subgroup 0..7
    const int q  = t & 31;   // float4 slot in row

    // ---- phase 1: gather. All 16 loads issued before any reduction. ----
    const float4* __restrict__ e4 = reinterpret_cast<const float4*>(emb);
    float4 l0 = e4[(size_t)idxL[     n0] * 32 + q];
    float4 l1 = e4[(size_t)idxL[ 8 + n0] * 32 + q];
    float4 l2 = e4[(size_t)idxL[16 + n0] * 32 + q];
    float4 l3 = e4[(size_t)idxL[24 + n0] * 32 + q];
    float4 l4 = e4[(size_t)idxL[32 + n0] * 32 + q];
    float4 l5 = e4[(size_t)idxL[40 + n0] * 32 + q];
    float4 l6 = e4[(size_t)idxL[48 + n0] * 32 + q];
    float4 l7 = e4[(size_t)idxL[56 + n0] * 32 + q];
    float4 r0 = e4[(size_t)idxR[     n0] * 32 + q];
    float4 r1 = e4[(size_t)idxR[ 8 + n0] * 32 + q];
    float4 r2 = e4[(size_t)idxR[16 + n0] * 32 + q];
    float4 r3 = e4[(size_t)idxR[24 + n0] * 32 + q];
    float4 r4 = e4[(size_t)idxR[32 + n0] * 32 + q];
    float4 r5 = e4[(size_t)idxR[40 + n0] * 32 + q];
    float4 r6 = e4[(size_t)idxR[48 + n0] * 32 + q];
    float4 r7 = e4[(size_t)idxR[56 + n0] * 32 + q];

    float4 aL = fmax4(fmax4(fmax4(l0, l1), fmax4(l2, l3)),
                      fmax4(fmax4(l4, l5), fmax4(l6, l7)));
    float4 aR = fmax4(fmax4(fmax4(r0, r1), fmax4(r2, r3)),
                      fmax4(fmax4(r4, r5), fmax4(r6, r7)));

    // combine lane and lane+32 (n0 even/odd pair within the wave)
    aL.x = fmaxf(aL.x, __shfl_xor(aL.x, 32));
    aL.y = fmaxf(aL.y, __shfl_xor(aL.y, 32));
    aL.z = fmaxf(aL.z, __shfl_xor(aL.z, 32));
    aL.w = fmaxf(aL.w, __shfl_xor(aL.w, 32));
    aR.x = fmaxf(aR.x, __shfl_xor(aR.x, 32));
    aR.y = fmaxf(aR.y, __shfl_xor(aR.y, 32));
    aR.z = fmaxf(aR.z, __shfl_xor(aR.z, 32));
    aR.w = fmaxf(aR.w, __shfl_xor(aR.w, 32));

    if (lane < 32) {                 // lanes 0..31: q == lane, n0 == 2w
        const int o = w * 32 + lane;
        red[0][0][o] = aL.x; red[0][1][o] = aL.y;
        red[0][2][o] = aL.z; red[0][3][o] = aL.w;
        red[1][0][o] = aR.x; red[1][1][o] = aR.y;
        red[1][2][o] = aR.z; red[1][3][o] = aR.w;
    }
    __syncthreads();

    // ---- phase 2: reduce 4 wave-partials per slot (threads 0..63) ----
    if (t < 64) {
        const int side = t >> 5;
        const int qq   = t & 31;
        float4 m;
        m.x = fmaxf(fmaxf(red[side][0][qq],      red[side][0][32 + qq]),
                    fmaxf(red[side][0][64 + qq], red[side][0][96 + qq]));
        m.y = fmaxf(fmaxf(red[side][1][qq],      red[side][1][32 + qq]),
                    fmaxf(red[side][1][64 + qq], red[side][1][96 + qq]));
        m.z = fmaxf(fmaxf(red[side][2][qq],      red[side][2][32 + qq]),
                    fmaxf(red[side][2][64 + qq], red[side][2][96 + qq]));
        m.w = fmaxf(fmaxf(red[side][3][qq],      red[side][3][32 + qq]),
                    fmaxf(red[side][3][64 + qq], red[side][3][96 + qq]));
        P4[side][qq] = m;
    }
    __syncthreads();

    // ---- phase 3: matvec. (side = t&1, e = t>>1) ----
    float acc;
    {
        const int side = t & 1;
        const int e    = t >> 1;
        acc = bias[e];
        const float4* __restrict__ wr =
            reinterpret_cast<const float4*>(W) + (size_t)e * 32;
        const float4* __restrict__ pv = P4[side];
        #pragma unroll 8
        for (int fi = 0; fi < 32; ++fi) {
            const float4 wv = wr[fi];
            const float4 p  = pv[fi];
            acc = fmaf(p.x, wv.x, acc);
            acc = fmaf(p.y, wv.y, acc);
            acc = fmaf(p.z, wv.z, acc);
            acc = fmaf(p.w, wv.w, acc);
        }
    }

    // ---- phase 4: pair exchange -> cos/loss ----
    {
        const float other = __shfl_xor(acc, 1);
        const float l = (t & 1) ? other : acc;
        const float r = (t & 1) ? acc   : other;
        float dot = l * r;
        float nl  = l * l;
        float nr  = r * r;
        #pragma unroll
        for (int off = 1; off < 64; off <<= 1) {
            dot += __shfl_xor(dot, off);
            nl  += __shfl_xor(nl,  off);
            nr  += __shfl_xor(nr,  off);
        }
        if (lane == 0) {             // wave sum = 2 * sum over its 32 e's
            wred[0][w] = dot; wred[1][w] = nl; wred[2][w] = nr;
        }
    }
    __syncthreads();

    if (t == 0) {
        const float dd = 0.5f * (wred[0][0] + wred[0][1] + wred[0][2] + wred[0][3]);
        const float ll = 0.5f * (wred[1][0] + wred[1][1] + wred[1][2] + wred[1][3]);
        const float rr = 0.5f * (wred[2][0] + wred[2][1] + wred[2][2] + wred[2][3]);
        const float nlv = fmaxf(sqrtf(ll), 1e-6f);
        const float nrv = fmaxf(sqrtf(rr), 1e-6f);
        const float c   = dd / (nlv * nrv);
        out[1 + g] = c;
        const float lab = label[g];
        const float mm  = fmaxf(1.0f - c, 0.0f);
        const float loss = 0.5f * ((1.0f - lab) * c * c + lab * mm * mm);
        atomicAdd(out, loss * INV_B);
    }
}

// ---------------------------------------------------------------------------
// Inputs (setup_inputs order):
// 0 left_x (N int32), 1 left_graph_index (B), 2 right_x (N), 3 right_graph_index,
// 4 left_x_batch (N), 5 right_x_batch (N), 6 label (B f32),
// 7 emb_table (V*E f32), 8 W (E*E f32), 9 b (E f32)
// Output: [0] = sim_loss, [1..B] = cos  (float32, out_size = B+1)
// ---------------------------------------------------------------------------
extern "C" void kernel_launch(void* const* d_in, const int* in_sizes, int n_in,
                              void* d_out, int out_size, void* d_ws, size_t ws_size,
                              hipStream_t stream)
{
    const int*   lx    = (const int*)d_in[0];
    const int*   rx    = (const int*)d_in[2];
    const float* label = (const float*)d_in[6];
    const float* emb   = (const float*)d_in[7];
    const float* W     = (const float*)d_in[8];
    const float* bias  = (const float*)d_in[9];

    float* out = (float*)d_out;   // [0]=loss (atomic-accumulated), [1..B]=cos

    hipMemsetAsync(out, 0, sizeof(float), stream);

    fused_graph_sim_k<<<B_GRAPHS, 256, 0, stream>>>(
        lx, rx, emb, W, bias, label, out);
}

// Round 6
// 164.523 us; speedup vs baseline: 1.0043x; 1.0043x over previous
//
#include <hip/hip_runtime.h>
#include <math.h>

#define B_GRAPHS 4096
#define NPG 64
#define E_DIM 128
#define INV_B (1.0f / 4096.0f)

static __device__ __forceinline__ float4 fmax4(float4 a, float4 b) {
    return make_float4(fmaxf(a.x, b.x), fmaxf(a.y, b.y),
                       fmaxf(a.z, b.z), fmaxf(a.w, b.w));
}

// ---------------------------------------------------------------------------
// One block per graph (4096 blocks x 256 threads = 4 waves).
// Per side (L then R, shared 32 KB staging buffer):
//   stage: wave w issues 8 async global_load_lds (1 KB each: lanes 0-31 row
//          2j, lanes 32-63 row 2j+1; per-lane GLOBAL addr = the gather,
//          linear LDS dest = HW contract). Zero VGPR results -> compiler
//          cannot serialize them; 8 outstanding per wave guaranteed.
//   reduce: conflict-free ds_read_b128 sweep (consecutive lanes ->
//          consecutive 16B), register fmax, shfl_xor(32), per-wave partials,
//          combine -> pooled P4[side][32].
// Then matvec (W rows from L1/L2) + pair-shuffle cos/loss tail.
// LDS ~36 KB -> 4 blocks/CU; in-flight 16 waves x 8 KB = 128 KB per CU.
// ---------------------------------------------------------------------------
__global__ __launch_bounds__(256) void fused_graph_sim_k(
    const int* __restrict__ lx, const int* __restrict__ rx,
    const float* __restrict__ emb, const float* __restrict__ W,
    const float* __restrict__ bias, const float* __restrict__ label,
    float* __restrict__ out)
{
    const int g    = blockIdx.x;
    const int t    = threadIdx.x;
    const int w    = t >> 6;
    const int lane = t & 63;

    __shared__ int    idxs[2][NPG];
    __shared__ float  rows[NPG][E_DIM];   // 32 KB staging, one side at a time
    __shared__ float4 part[4][32];        // per-wave partial maxes
    __shared__ float4 P4[2][32];          // pooled, float4 view of [2][128]
    __shared__ float  wred[3][4];         // per-wave dot/nl/nr partials

    if (t < NPG)          idxs[0][t]       = lx[g * NPG + t];
    else if (t < 2 * NPG) idxs[1][t - NPG] = rx[g * NPG + (t - NPG)];
    __syncthreads();

    const int q     = lane & 31;   // float4 slot within a row
    const int rbase = w * 16;      // this wave's 16-row stripe

    #pragma unroll
    for (int side = 0; side < 2; ++side) {
        // ---- async stage: 8 x 1 KB global_load_lds per wave ----
        #pragma unroll
        for (int j = 0; j < 8; ++j) {
            const int r = rbase + 2 * j + (lane >> 5);
            const float* gsrc =
                emb + (size_t)idxs[side][r] * E_DIM + q * 4;
            __builtin_amdgcn_global_load_lds(
                (const __attribute__((address_space(1))) void*)gsrc,
                (__attribute__((address_space(3))) void*)&rows[rbase + 2 * j][0],
                16, 0, 0);
        }
        asm volatile("s_waitcnt vmcnt(0)" ::: "memory");
        __syncthreads();

        // ---- reduce: wave w max-reduces its 16 rows ----
        float4 m = make_float4(-INFINITY, -INFINITY, -INFINITY, -INFINITY);
        #pragma unroll
        for (int k = 0; k < 8; ++k) {
            const int r = rbase + 2 * k + (lane >> 5);
            m = fmax4(m, *reinterpret_cast<const float4*>(&rows[r][q * 4]));
        }
        m.x = fmaxf(m.x, __shfl_xor(m.x, 32));
        m.y = fmaxf(m.y, __shfl_xor(m.y, 32));
        m.z = fmaxf(m.z, __shfl_xor(m.z, 32));
        m.w = fmaxf(m.w, __shfl_xor(m.w, 32));
        if (lane < 32) part[w][q] = m;
        __syncthreads();

        if (t < 32)
            P4[side][t] = fmax4(fmax4(part[0][t], part[1][t]),
                                fmax4(part[2][t], part[3][t]));
        __syncthreads();   // also protects rows[] reuse by the next side
    }

    // ---- matvec: (side = t&1, e = t>>1), W rows stream through L1/L2 ----
    float acc;
    {
        const int side = t & 1;
        const int e    = t >> 1;
        acc = bias[e];
        const float4* __restrict__ wr =
            reinterpret_cast<const float4*>(W) + (size_t)e * 32;
        const float4* __restrict__ pv = P4[side];
        #pragma unroll 8
        for (int fi = 0; fi < 32; ++fi) {
            const float4 wv = wr[fi];
            const float4 p  = pv[fi];
            acc = fmaf(p.x, wv.x, acc);
            acc = fmaf(p.y, wv.y, acc);
            acc = fmaf(p.z, wv.z, acc);
            acc = fmaf(p.w, wv.w, acc);
        }
    }

    // ---- tail: pair exchange -> dot/norms -> cos -> loss ----
    {
        const float other = __shfl_xor(acc, 1);
        const float l = (t & 1) ? other : acc;
        const float r = (t & 1) ? acc   : other;
        float dot = l * r;
        float nl  = l * l;
        float nr  = r * r;
        #pragma unroll
        for (int off = 1; off < 64; off <<= 1) {
            dot += __shfl_xor(dot, off);
            nl  += __shfl_xor(nl,  off);
            nr  += __shfl_xor(nr,  off);
        }
        if (lane == 0) {   // wave sum counts each e twice -> halve later
            wred[0][w] = dot; wred[1][w] = nl; wred[2][w] = nr;
        }
    }
    __syncthreads();

    if (t == 0) {
        const float dd = 0.5f * (wred[0][0] + wred[0][1] + wred[0][2] + wred[0][3]);
        const float ll = 0.5f * (wred[1][0] + wred[1][1] + wred[1][2] + wred[1][3]);
        const float rr = 0.5f * (wred[2][0] + wred[2][1] + wred[2][2] + wred[2][3]);
        const float nlv = fmaxf(sqrtf(ll), 1e-6f);
        const float nrv = fmaxf(sqrtf(rr), 1e-6f);
        const float c   = dd / (nlv * nrv);
        out[1 + g] = c;
        const float lab  = label[g];
        const float mm   = fmaxf(1.0f - c, 0.0f);
        const float loss = 0.5f * ((1.0f - lab) * c * c + lab * mm * mm);
        atomicAdd(out, loss * INV_B);
    }
}

// ---------------------------------------------------------------------------
// Inputs (setup_inputs order):
// 0 left_x (N int32), 1 left_graph_index (B), 2 right_x (N), 3 right_graph_index,
// 4 left_x_batch (N), 5 right_x_batch (N), 6 label (B f32),
// 7 emb_table (V*E f32), 8 W (E*E f32), 9 b (E f32)
// Output: [0] = sim_loss, [1..B] = cos  (float32, out_size = B+1)
// ---------------------------------------------------------------------------
extern "C" void kernel_launch(void* const* d_in, const int* in_sizes, int n_in,
                              void* d_out, int out_size, void* d_ws, size_t ws_size,
                              hipStream_t stream)
{
    const int*   lx    = (const int*)d_in[0];
    const int*   rx    = (const int*)d_in[2];
    const float* label = (const float*)d_in[6];
    const float* emb   = (const float*)d_in[7];
    const float* W     = (const float*)d_in[8];
    const float* bias  = (const float*)d_in[9];

    float* out = (float*)d_out;   // [0]=loss (atomic-accumulated), [1..B]=cos

    hipMemsetAsync(out, 0, sizeof(float), stream);

    fused_graph_sim_k<<<B_GRAPHS, 256, 0, stream>>>(
        lx, rx, emb, W, bias, label, out);
}